// Round 12
// baseline (323.642 us; speedup 1.0000x reference)
//
#include <hip/hip_runtime.h>
#include <hip/hip_bf16.h>

typedef unsigned short u16;
typedef __attribute__((ext_vector_type(8))) short short8;   // 8 bf16 = 4 VGPRs
typedef __attribute__((ext_vector_type(4))) float f32x4;

#if __has_builtin(__builtin_amdgcn_exp2f)
#define EXP2F(x) __builtin_amdgcn_exp2f(x)
#else
#define EXP2F(x) exp2f(x)
#endif

__device__ __forceinline__ float bf2f(u16 v) {
    union { unsigned u; float f; } c; c.u = ((unsigned)v) << 16; return c.f;
}
__device__ __forceinline__ u16 f2bf(float f) {
    union { float f; unsigned u; } c; c.f = f;
    unsigned r = c.u + 0x7fffu + ((c.u >> 16) & 1u);   // RNE
    return (u16)(r >> 16);
}
__device__ __forceinline__ uint4 pack8(const float4 a, const float4 b) {
    uint4 r;
    r.x = (unsigned)f2bf(a.x) | ((unsigned)f2bf(a.y) << 16);
    r.y = (unsigned)f2bf(a.z) | ((unsigned)f2bf(a.w) << 16);
    r.z = (unsigned)f2bf(b.x) | ((unsigned)f2bf(b.y) << 16);
    r.w = (unsigned)f2bf(b.z) | ((unsigned)f2bf(b.w) << 16);
    return r;
}
__device__ __forceinline__ void gl_lds16(const u16* g, u16* l) {
    __builtin_amdgcn_global_load_lds((const __attribute__((address_space(1))) unsigned int*)g,
                                     (__attribute__((address_space(3))) unsigned int*)l, 16, 0, 0);
}

// ---- one-shot f32 -> bf16 conversion of x + 4 weights -------------------
__global__ __launch_bounds__(256) void convert_all(const float* __restrict__ x,
                                                   const float* __restrict__ wq,
                                                   const float* __restrict__ wk,
                                                   const float* __restrict__ wv,
                                                   const float* __restrict__ wo,
                                                   u16* xb, u16* wqb, u16* wkb, u16* wvb, u16* wob) {
    size_t i8 = ((size_t)blockIdx.x * 256 + threadIdx.x) * 8;
    const float* src; u16* dst; size_t off;
    if (i8 < 8388608) { src = x; dst = xb; off = i8; }
    else {
        size_t idx = i8 - 8388608;
        int w = (int)(idx >> 20); off = idx & 1048575;
        src = (w == 0) ? wq : (w == 1) ? wk : (w == 2) ? wv : wo;
        dst = (w == 0) ? wqb : (w == 1) ? wkb : (w == 2) ? wvb : wob;
    }
    float4 a = *(const float4*)&src[off];
    float4 b = *(const float4*)&src[off + 4];
    *(uint4*)&dst[off] = pack8(a, b);
}

// ---- single-output 128x128 bf16 GEMM core (r5-verified), 4 waves --------
// BK=64, two barriers per K-step, 0 bank conflicts. Used by gemm_out where
// 2 blocks/CU TLP (24 KB LDS, 256 thr) hides the barrier drains.
__device__ __forceinline__ void gemm_core(const u16* __restrict__ A, const u16* __restrict__ B,
                                          int m0, int n0, u16* As, u16* Bs, f32x4 acc[4][4]) {
    const int tid = threadIdx.x;
    const int wv = tid >> 6, lane = tid & 63, lr = lane & 15, quad = lane >> 4;
    const int srow = lane >> 3;              // 0..7
    const int scg  = (lane & 7) ^ srow;      // swizzled col-group loaded by this lane
    const int wm = (wv >> 1) * 64, wn = (wv & 1) * 64;

    for (int kt = 0; kt < 1024; kt += 64) {
        __syncthreads();
        #pragma unroll
        for (int t = 0; t < 4; ++t) {
            int r = wv * 32 + t * 8;
            gl_lds16(&A[(size_t)(m0 + r + srow) * 1024 + kt + scg * 8], &As[r * 64]);
            gl_lds16(&B[(size_t)(n0 + r + srow) * 1024 + kt + scg * 8], &Bs[r * 64]);
        }
        __syncthreads();
        #pragma unroll
        for (int c = 0; c < 2; ++c) {
            short8 af[4], bf[4];
            #pragma unroll
            for (int mi = 0; mi < 4; ++mi)
                af[mi] = *(const short8*)&As[(wm + mi * 16 + lr) * 64 + (((c * 4 + quad) ^ (lr & 7)) * 8)];
            #pragma unroll
            for (int ni = 0; ni < 4; ++ni)
                bf[ni] = *(const short8*)&Bs[(wn + ni * 16 + lr) * 64 + (((c * 4 + quad) ^ (lr & 7)) * 8)];
            #pragma unroll
            for (int mi = 0; mi < 4; ++mi)
                #pragma unroll
                for (int ni = 0; ni < 4; ++ni)
                    acc[mi][ni] = __builtin_amdgcn_mfma_f32_16x16x32_bf16(af[mi], bf[ni], acc[mi][ni], 0, 0, 0);
        }
    }
}

// ---- DUAL-output 128x128 bf16 GEMM core, 2-barrier K-step (r7-verified) --
// One A-tile staged once vs TWO B-tiles => 32 MFMAs per barrier-pair. 8 waves
// (4M x 2N), per-wave 32x64 per output (acc 2x[2][4] = 64 VGPR). 0 conflicts.
// Requires >=2 blocks/CU to hide drains (qkv runs 3/CU).
__device__ __forceinline__ void core_dual(const u16* __restrict__ A,
                                          const u16* __restrict__ B0,
                                          const u16* __restrict__ B1,
                                          int m0, int n0a, int n0b,
                                          u16* As, u16* Bs0, u16* Bs1,
                                          f32x4 acc0[2][4], f32x4 acc1[2][4]) {
    const int tid = threadIdx.x;
    const int wid = tid >> 6, lane = tid & 63, lr = lane & 15, quad = lane >> 4;
    const int srow = lane >> 3;              // 0..7
    const int scg  = (lane & 7) ^ srow;      // swizzled col-group loaded by this lane
    const int wm = (wid >> 1) * 32, wn = (wid & 1) * 64;
    const int r0 = wid * 16;                 // this wave's 16-row staging slot

    for (int kt = 0; kt < 1024; kt += 64) {
        __syncthreads();
        #pragma unroll
        for (int h = 0; h < 2; ++h) {
            int r = r0 + h * 8;
            gl_lds16(&A [(size_t)(m0  + r + srow) * 1024 + kt + scg * 8], &As [r * 64]);
            gl_lds16(&B0[(size_t)(n0a + r + srow) * 1024 + kt + scg * 8], &Bs0[r * 64]);
            gl_lds16(&B1[(size_t)(n0b + r + srow) * 1024 + kt + scg * 8], &Bs1[r * 64]);
        }
        __syncthreads();
        #pragma unroll
        for (int c = 0; c < 2; ++c) {
            short8 af[2], bf[4];
            #pragma unroll
            for (int mi = 0; mi < 2; ++mi)
                af[mi] = *(const short8*)&As[(wm + mi * 16 + lr) * 64 + (((c * 4 + quad) ^ (lr & 7)) * 8)];
            #pragma unroll
            for (int ni = 0; ni < 4; ++ni)
                bf[ni] = *(const short8*)&Bs0[(wn + ni * 16 + lr) * 64 + (((c * 4 + quad) ^ (lr & 7)) * 8)];
            #pragma unroll
            for (int mi = 0; mi < 2; ++mi)
                #pragma unroll
                for (int ni = 0; ni < 4; ++ni)
                    acc0[mi][ni] = __builtin_amdgcn_mfma_f32_16x16x32_bf16(af[mi], bf[ni], acc0[mi][ni], 0, 0, 0);
            #pragma unroll
            for (int ni = 0; ni < 4; ++ni)
                bf[ni] = *(const short8*)&Bs1[(wn + ni * 16 + lr) * 64 + (((c * 4 + quad) ^ (lr & 7)) * 8)];
            #pragma unroll
            for (int mi = 0; mi < 2; ++mi)
                #pragma unroll
                for (int ni = 0; ni < 4; ++ni)
                    acc1[mi][ni] = __builtin_amdgcn_mfma_f32_16x16x32_bf16(af[mi], bf[ni], acc1[mi][ni], 0, 0, 0);
        }
    }
}

// ---- fused QKV projection, dual-output blocks, XCD-pinned (r7-verified) --
// 768 blocks x 512 thr = exactly 3 blocks/CU of uniform work.
//  bid<512 (z01): x m-panel staged once vs wq AND wk -> Q and K tiles.
//  bid>=512 (z2f): wv m-tile staged once vs TWO x n-tiles -> 2 Vt tiles.
__global__ __launch_bounds__(512, 4) void gemm_qkv(const u16* __restrict__ xb,
                                                   const u16* __restrict__ wq,
                                                   const u16* __restrict__ wk,
                                                   const u16* __restrict__ wv,
                                                   u16* __restrict__ Qb, u16* __restrict__ Kb,
                                                   u16* __restrict__ Vtb) {
    __shared__ __align__(16) u16 As [8192];
    __shared__ __align__(16) u16 Bs0[8192];
    __shared__ __align__(16) u16 Bs1[8192];
    const int bid = blockIdx.x;

    f32x4 acc0[2][4], acc1[2][4];
    #pragma unroll
    for (int a = 0; a < 2; ++a)
        #pragma unroll
        for (int b = 0; b < 4; ++b) { acc0[a][b] = 0; acc1[a][b] = 0; }

    const int lane = threadIdx.x & 63, lr = lane & 15, quad = lane >> 4;
    const int wid = threadIdx.x >> 6;
    const int wm = (wid >> 1) * 32, wn = (wid & 1) * 64;

    if (bid < 512) {                          // ---- z0+z1: Q and K ----
        const int xcd = bid & 7;
        const int i   = bid >> 3;             // 0..63
        const int m0  = (xcd * 8 + (i & 7)) * 128;
        const int n0  = (i >> 3) * 128;
        core_dual(xb, wq, wk, m0, n0, n0, As, Bs0, Bs1, acc0, acc1);
        #pragma unroll
        for (int mi = 0; mi < 2; ++mi)
            #pragma unroll
            for (int ni = 0; ni < 4; ++ni)
                #pragma unroll
                for (int reg = 0; reg < 4; ++reg) {
                    int row = m0 + wm + mi * 16 + quad * 4 + reg;
                    int col = n0 + wn + ni * 16 + lr;
                    int bhh = (row >> 11) * 16 + (col >> 6);
                    size_t o = (size_t)bhh * 131072 + (size_t)(row & 2047) * 64 + (col & 63);
                    Qb[o] = f2bf(acc0[mi][ni][reg] * 0.18033688f);   // 0.125*log2(e)
                    Kb[o] = f2bf(acc1[mi][ni][reg]);
                }
    } else {                                  // ---- z2 pair: two Vt tiles ----
        const int t   = bid - 512;
        const int xcd = t & 7;
        const int j   = t >> 3;               // 0..31
        const int m0  = (j & 7) * 128;        // wv rows
        const int np  = xcd * 4 + (j >> 3);   // x n-pair panel (256 rows)
        const int n0a = np * 256, n0b = np * 256 + 128;
        core_dual(wv, xb, xb, m0, n0a, n0b, As, Bs0, Bs1, acc0, acc1);
        #pragma unroll
        for (int half = 0; half < 2; ++half) {
            const int nb = half ? n0b : n0a;
            #pragma unroll
            for (int mi = 0; mi < 2; ++mi)
                #pragma unroll
                for (int ni = 0; ni < 4; ++ni)
                    #pragma unroll
                    for (int reg = 0; reg < 4; ++reg) {
                        int row = m0 + wm + mi * 16 + quad * 4 + reg;   // d-dim (0..1023)
                        int col = nb + wn + ni * 16 + lr;               // s-dim (0..8191)
                        int bhh = (col >> 11) * 16 + (row >> 6);
                        float v = half ? acc1[mi][ni][reg] : acc0[mi][ni][reg];
                        Vtb[(size_t)bhh * 131072 + (size_t)(row & 63) * 2048 + (col & 2047)] = f2bf(v);
                    }
        }
    }
}

// ---- output projection: r5-verified config, 512 blocks x 256 thr --------
// 2 blocks/CU (24 KB LDS) -> TLP hides the 2-barrier drains.
__global__ __launch_bounds__(256) void gemm_out(const u16* __restrict__ Ob,
                                                const u16* __restrict__ wo,
                                                float* __restrict__ C) {
    __shared__ __align__(16) u16 As[8192];
    __shared__ __align__(16) u16 Bs[8192];
    const int bid = blockIdx.x;
    const int xcd = bid & 7;
    const int i   = bid >> 3;            // 0..63
    const int mp  = xcd * 8 + (i & 7);   // m fastest within XCD
    const int m0  = mp * 128, n0 = (i >> 3) * 128;

    f32x4 acc[4][4];
    #pragma unroll
    for (int a = 0; a < 4; ++a)
        #pragma unroll
        for (int j = 0; j < 4; ++j) acc[a][j] = 0;

    gemm_core(Ob, wo, m0, n0, As, Bs, acc);

    const int lane = threadIdx.x & 63, lr = lane & 15, quad = lane >> 4;
    const int wv4 = threadIdx.x >> 6;
    const int wm = (wv4 >> 1) * 64, wn = (wv4 & 1) * 64;
    #pragma unroll
    for (int mi = 0; mi < 4; ++mi)
        #pragma unroll
        for (int ni = 0; ni < 4; ++ni)
            #pragma unroll
            for (int reg = 0; reg < 4; ++reg) {
                int row = m0 + wm + mi * 16 + quad * 4 + reg;
                int col = n0 + wn + ni * 16 + lr;
                C[(size_t)row * 1024 + col] = acc[mi][ni][reg];
            }
}

// ---- block-cooperative flash attention, 8 waves (256 q-rows) per block --
// V is NOT staged through LDS (guide common-mistake #7 / m169): the Vt slice
// per bh is 256 KB, XCD-pinned L2-resident, and V fragments are single-use
// per wave. The 8 vf dwordx4 loads are issued right after the QK cluster so
// the mask+exp2+pack+Ps chain (~300 cyc) hides the ~200 cyc L2 latency. The
// swizzles cancel: staged Vbuf read == Vt[base + (dmi*16+lr)*2048 + j*64 +
// (c*4+quad)*8] (store/read mapping composition). HBM traffic unchanged.
// LDS 64->48 KB; K staging/prefetch and all other paths identical to r9.
__global__ __launch_bounds__(512, 4) void attn_flash(const u16* __restrict__ Q,
                                                     const u16* __restrict__ K,
                                                     const u16* __restrict__ Vt,
                                                     u16* __restrict__ O) {
    __shared__ __align__(16) u16 Kbuf[2][4096];    // 64 keys x 64 d, swizzled
    __shared__ __align__(16) u16 Ps[8][2048];      // per-wave P (32 q x 64 k), swizzled

    const int tid = threadIdx.x, wave = tid >> 6, lane = tid & 63;
    const int lr = lane & 15, quad = lane >> 4;
    const int bh = blockIdx.x & 63;                // bh%8 pinned -> XCD-local K/V in L2
    const int p  = blockIdx.x >> 6;                // 0..7
    const int qt8 = (p < 4) ? (7 - p) : (p - 4);   // first half heavy, second light
    const int qbase = qt8 * 256 + wave * 32;
    const size_t base = (size_t)bh * 131072;

    const int srow = lane >> 3;                    // 0..7
    const int scg  = (lane & 7) ^ srow;            // swizzled col-group

    const short8 onesv = {0x3f80, 0x3f80, 0x3f80, 0x3f80, 0x3f80, 0x3f80, 0x3f80, 0x3f80};

    // Q fragments (B-operand): q = qbase + qmi*16 + lr, k-chunk = c*32+quad*8
    short8 qf[2][2];
    #pragma unroll
    for (int qmi = 0; qmi < 2; ++qmi)
        #pragma unroll
        for (int c = 0; c < 2; ++c)
            qf[qmi][c] = *(const short8*)&Q[base + (size_t)(qbase + qmi * 16 + lr) * 64 + c * 32 + quad * 8];

    f32x4 oacc[4][2];
    #pragma unroll
    for (int i = 0; i < 4; ++i) { oacc[i][0] = 0; oacc[i][1] = 0; }
    f32x4 lacc[2];
    lacc[0] = 0; lacc[1] = 0;                      // row-sum accumulators (MFMA ones)

    const int jmax = 4 * qt8 + 3;
    const int r0 = wave * 8;                       // this wave's 8-row staging group

    // stage K tile 0 into buffer 0 (each wave: one 1 KB load)
    gl_lds16(&K[base + (size_t)(r0 + srow) * 64 + scg * 8], &Kbuf[0][r0 * 64]);

    for (int j = 0; j <= jmax; ++j) {
        const int buf = j & 1;
        __syncthreads();                           // staged K tile j is ready
        if (j < jmax)                              // prefetch K j+1 (flies during compute)
            gl_lds16(&K[base + (size_t)((j + 1) * 64 + r0 + srow) * 64 + scg * 8], &Kbuf[buf ^ 1][r0 * 64]);

        if (j * 64 <= qbase + 31) {                // tile not fully masked for this wave
            f32x4 st[4][2];
            #pragma unroll
            for (int ni = 0; ni < 4; ++ni) { st[ni][0] = 0; st[ni][1] = 0; }
            __builtin_amdgcn_s_setprio(1);
            #pragma unroll
            for (int c = 0; c < 2; ++c) {
                short8 kf[4];
                #pragma unroll
                for (int ni = 0; ni < 4; ++ni)
                    kf[ni] = *(const short8*)&Kbuf[buf][(ni * 16 + lr) * 64 + (((c * 4 + quad) ^ (lr & 7)) * 8)];
                #pragma unroll
                for (int ni = 0; ni < 4; ++ni)
                    #pragma unroll
                    for (int qmi = 0; qmi < 2; ++qmi)
                        st[ni][qmi] = __builtin_amdgcn_mfma_f32_16x16x32_bf16(kf[ni], qf[qmi][c], st[ni][qmi], 0, 0, 0);
            }
            __builtin_amdgcn_s_setprio(0);

            // V fragments direct from L2 (issued here: softmax chain hides latency)
            short8 vfr[2][4];
            #pragma unroll
            for (int c = 0; c < 2; ++c)
                #pragma unroll
                for (int dmi = 0; dmi < 4; ++dmi)
                    vfr[c][dmi] = *(const short8*)&Vt[base + (size_t)(dmi * 16 + lr) * 2048 + j * 64 + (c * 4 + quad) * 8];

            if (j >= 4 * qt8) {                    // only the diagonal region masks
                #pragma unroll
                for (int ni = 0; ni < 4; ++ni)
                    #pragma unroll
                    for (int qmi = 0; qmi < 2; ++qmi)
                        #pragma unroll
                        for (int reg = 0; reg < 4; ++reg) {
                            int key = j * 64 + ni * 16 + quad * 4 + reg;
                            int q   = qbase + qmi * 16 + lr;
                            if (key > q) st[ni][qmi][reg] = -3.0e38f;   // exp2 -> 0
                        }
            }

            // P = exp2(st) directly; store truncated bf16 to Ps (same-wave region)
            #pragma unroll
            for (int qmi = 0; qmi < 2; ++qmi) {
                #pragma unroll
                for (int ni = 0; ni < 4; ++ni) {
                    unsigned u0 = __float_as_uint(EXP2F(st[ni][qmi][0]));
                    unsigned u1 = __float_as_uint(EXP2F(st[ni][qmi][1]));
                    unsigned u2 = __float_as_uint(EXP2F(st[ni][qmi][2]));
                    unsigned u3 = __float_as_uint(EXP2F(st[ni][qmi][3]));
                    uint2 pk;
                    pk.x = __builtin_amdgcn_perm(u1, u0, 0x07060302);
                    pk.y = __builtin_amdgcn_perm(u3, u2, 0x07060302);
                    int g8 = ni * 2 + (quad >> 1);
                    *(uint2*)&Ps[wave][qmi * 1024 + lr * 64 + ((g8 ^ (lr & 7)) * 8 + (quad & 1) * 4)] = pk;
                }
            }

            __builtin_amdgcn_s_setprio(1);
            #pragma unroll
            for (int c = 0; c < 2; ++c) {
                short8 pf[2];
                #pragma unroll
                for (int qmi = 0; qmi < 2; ++qmi)
                    pf[qmi] = *(const short8*)&Ps[wave][qmi * 1024 + lr * 64 + (((c * 4 + quad) ^ (lr & 7)) * 8)];
                #pragma unroll
                for (int dmi = 0; dmi < 4; ++dmi) {
                    #pragma unroll
                    for (int qmi = 0; qmi < 2; ++qmi)
                        oacc[dmi][qmi] = __builtin_amdgcn_mfma_f32_16x16x32_bf16(vfr[c][dmi], pf[qmi], oacc[dmi][qmi], 0, 0, 0);
                }
                #pragma unroll
                for (int qmi = 0; qmi < 2; ++qmi)
                    lacc[qmi] = __builtin_amdgcn_mfma_f32_16x16x32_bf16(onesv, pf[qmi], lacc[qmi], 0, 0, 0);
            }
            __builtin_amdgcn_s_setprio(0);
        }
    }

    const int b = bh >> 4, h = bh & 15;
    #pragma unroll
    for (int qmi = 0; qmi < 2; ++qmi) {
        float rl = 1.0f / lacc[qmi][0];            // l[q=lr]; all regs identical
        int s = qbase + qmi * 16 + lr;
        #pragma unroll
        for (int dmi = 0; dmi < 4; ++dmi) {
            unsigned o0 = f2bf(oacc[dmi][qmi][0] * rl);
            unsigned o1 = f2bf(oacc[dmi][qmi][1] * rl);
            unsigned o2 = f2bf(oacc[dmi][qmi][2] * rl);
            unsigned o3 = f2bf(oacc[dmi][qmi][3] * rl);
            uint2 pk;
            pk.x = o0 | (o1 << 16);
            pk.y = o2 | (o3 << 16);
            *(uint2*)&O[((size_t)(b * 2048 + s)) * 1024 + h * 64 + dmi * 16 + quad * 4] = pk;
        }
    }
}

extern "C" void kernel_launch(void* const* d_in, const int* in_sizes, int n_in,
                              void* d_out, int out_size, void* d_ws, size_t ws_size,
                              hipStream_t stream) {
    const float* x  = (const float*)d_in[0];
    const float* Wq = (const float*)d_in[1];
    const float* Wk = (const float*)d_in[2];
    const float* Wv = (const float*)d_in[3];
    const float* Wo = (const float*)d_in[4];

    u16* xb  = (u16*)d_ws;
    u16* wqb = xb + 8388608;
    u16* wkb = wqb + 1048576;
    u16* wvb = wkb + 1048576;
    u16* wob = wvb + 1048576;
    u16* Qb  = wob + 1048576;
    u16* Kb  = Qb + 8388608;
    u16* Vtb = Kb + 8388608;
    u16* Ob  = xb;   // alias: x dead after gemm_qkv

    convert_all<<<6144, 256, 0, stream>>>(x, Wq, Wk, Wv, Wo, xb, wqb, wkb, wvb, wob);

    gemm_qkv<<<768, 512, 0, stream>>>(xb, wqb, wkb, wvb, Qb, Kb, Vtb);

    attn_flash<<<512, 512, 0, stream>>>(Qb, Kb, Vtb, Ob);

    gemm_out<<<512, 256, 0, stream>>>(Ob, wob, (float*)d_out);
}

// Round 13
// 226.550 us; speedup vs baseline: 1.4286x; 1.4286x over previous
//
#include <hip/hip_runtime.h>
#include <hip/hip_bf16.h>

typedef unsigned short u16;
typedef __attribute__((ext_vector_type(8))) short short8;   // 8 bf16 = 4 VGPRs
typedef __attribute__((ext_vector_type(4))) float f32x4;

#if __has_builtin(__builtin_amdgcn_exp2f)
#define EXP2F(x) __builtin_amdgcn_exp2f(x)
#else
#define EXP2F(x) exp2f(x)
#endif

__device__ __forceinline__ float bf2f(u16 v) {
    union { unsigned u; float f; } c; c.u = ((unsigned)v) << 16; return c.f;
}
__device__ __forceinline__ u16 f2bf(float f) {
    union { float f; unsigned u; } c; c.f = f;
    unsigned r = c.u + 0x7fffu + ((c.u >> 16) & 1u);   // RNE
    return (u16)(r >> 16);
}
__device__ __forceinline__ uint4 pack8(const float4 a, const float4 b) {
    uint4 r;
    r.x = (unsigned)f2bf(a.x) | ((unsigned)f2bf(a.y) << 16);
    r.y = (unsigned)f2bf(a.z) | ((unsigned)f2bf(a.w) << 16);
    r.z = (unsigned)f2bf(b.x) | ((unsigned)f2bf(b.y) << 16);
    r.w = (unsigned)f2bf(b.z) | ((unsigned)f2bf(b.w) << 16);
    return r;
}
__device__ __forceinline__ void gl_lds16(const u16* g, u16* l) {
    __builtin_amdgcn_global_load_lds((const __attribute__((address_space(1))) unsigned int*)g,
                                     (__attribute__((address_space(3))) unsigned int*)l, 16, 0, 0);
}

// ---- one-shot f32 -> bf16 conversion of x + 4 weights -------------------
__global__ __launch_bounds__(256) void convert_all(const float* __restrict__ x,
                                                   const float* __restrict__ wq,
                                                   const float* __restrict__ wk,
                                                   const float* __restrict__ wv,
                                                   const float* __restrict__ wo,
                                                   u16* xb, u16* wqb, u16* wkb, u16* wvb, u16* wob) {
    size_t i8 = ((size_t)blockIdx.x * 256 + threadIdx.x) * 8;
    const float* src; u16* dst; size_t off;
    if (i8 < 8388608) { src = x; dst = xb; off = i8; }
    else {
        size_t idx = i8 - 8388608;
        int w = (int)(idx >> 20); off = idx & 1048575;
        src = (w == 0) ? wq : (w == 1) ? wk : (w == 2) ? wv : wo;
        dst = (w == 0) ? wqb : (w == 1) ? wkb : (w == 2) ? wvb : wob;
    }
    float4 a = *(const float4*)&src[off];
    float4 b = *(const float4*)&src[off + 4];
    *(uint4*)&dst[off] = pack8(a, b);
}

// ---- single-output 128x128 bf16 GEMM core (r5-verified), 4 waves --------
// BK=64, two barriers per K-step, 0 bank conflicts. Used by gemm_out where
// 2 blocks/CU TLP (24 KB LDS, 256 thr) hides the barrier drains.
__device__ __forceinline__ void gemm_core(const u16* __restrict__ A, const u16* __restrict__ B,
                                          int m0, int n0, u16* As, u16* Bs, f32x4 acc[4][4]) {
    const int tid = threadIdx.x;
    const int wv = tid >> 6, lane = tid & 63, lr = lane & 15, quad = lane >> 4;
    const int srow = lane >> 3;              // 0..7
    const int scg  = (lane & 7) ^ srow;      // swizzled col-group loaded by this lane
    const int wm = (wv >> 1) * 64, wn = (wv & 1) * 64;

    for (int kt = 0; kt < 1024; kt += 64) {
        __syncthreads();
        #pragma unroll
        for (int t = 0; t < 4; ++t) {
            int r = wv * 32 + t * 8;
            gl_lds16(&A[(size_t)(m0 + r + srow) * 1024 + kt + scg * 8], &As[r * 64]);
            gl_lds16(&B[(size_t)(n0 + r + srow) * 1024 + kt + scg * 8], &Bs[r * 64]);
        }
        __syncthreads();
        #pragma unroll
        for (int c = 0; c < 2; ++c) {
            short8 af[4], bf[4];
            #pragma unroll
            for (int mi = 0; mi < 4; ++mi)
                af[mi] = *(const short8*)&As[(wm + mi * 16 + lr) * 64 + (((c * 4 + quad) ^ (lr & 7)) * 8)];
            #pragma unroll
            for (int ni = 0; ni < 4; ++ni)
                bf[ni] = *(const short8*)&Bs[(wn + ni * 16 + lr) * 64 + (((c * 4 + quad) ^ (lr & 7)) * 8)];
            #pragma unroll
            for (int mi = 0; mi < 4; ++mi)
                #pragma unroll
                for (int ni = 0; ni < 4; ++ni)
                    acc[mi][ni] = __builtin_amdgcn_mfma_f32_16x16x32_bf16(af[mi], bf[ni], acc[mi][ni], 0, 0, 0);
        }
    }
}

// ---- DUAL-output 128x128 bf16 GEMM core, 2-barrier K-step (r7-verified) --
// One A-tile staged once vs TWO B-tiles => 32 MFMAs per barrier-pair. 8 waves
// (4M x 2N), per-wave 32x64 per output (acc 2x[2][4] = 64 VGPR). 0 conflicts.
// Requires >=2 blocks/CU to hide drains (qkv runs 3/CU).
__device__ __forceinline__ void core_dual(const u16* __restrict__ A,
                                          const u16* __restrict__ B0,
                                          const u16* __restrict__ B1,
                                          int m0, int n0a, int n0b,
                                          u16* As, u16* Bs0, u16* Bs1,
                                          f32x4 acc0[2][4], f32x4 acc1[2][4]) {
    const int tid = threadIdx.x;
    const int wid = tid >> 6, lane = tid & 63, lr = lane & 15, quad = lane >> 4;
    const int srow = lane >> 3;              // 0..7
    const int scg  = (lane & 7) ^ srow;      // swizzled col-group loaded by this lane
    const int wm = (wid >> 1) * 32, wn = (wid & 1) * 64;
    const int r0 = wid * 16;                 // this wave's 16-row staging slot

    for (int kt = 0; kt < 1024; kt += 64) {
        __syncthreads();
        #pragma unroll
        for (int h = 0; h < 2; ++h) {
            int r = r0 + h * 8;
            gl_lds16(&A [(size_t)(m0  + r + srow) * 1024 + kt + scg * 8], &As [r * 64]);
            gl_lds16(&B0[(size_t)(n0a + r + srow) * 1024 + kt + scg * 8], &Bs0[r * 64]);
            gl_lds16(&B1[(size_t)(n0b + r + srow) * 1024 + kt + scg * 8], &Bs1[r * 64]);
        }
        __syncthreads();
        #pragma unroll
        for (int c = 0; c < 2; ++c) {
            short8 af[2], bf[4];
            #pragma unroll
            for (int mi = 0; mi < 2; ++mi)
                af[mi] = *(const short8*)&As[(wm + mi * 16 + lr) * 64 + (((c * 4 + quad) ^ (lr & 7)) * 8)];
            #pragma unroll
            for (int ni = 0; ni < 4; ++ni)
                bf[ni] = *(const short8*)&Bs0[(wn + ni * 16 + lr) * 64 + (((c * 4 + quad) ^ (lr & 7)) * 8)];
            #pragma unroll
            for (int mi = 0; mi < 2; ++mi)
                #pragma unroll
                for (int ni = 0; ni < 4; ++ni)
                    acc0[mi][ni] = __builtin_amdgcn_mfma_f32_16x16x32_bf16(af[mi], bf[ni], acc0[mi][ni], 0, 0, 0);
            #pragma unroll
            for (int ni = 0; ni < 4; ++ni)
                bf[ni] = *(const short8*)&Bs1[(wn + ni * 16 + lr) * 64 + (((c * 4 + quad) ^ (lr & 7)) * 8)];
            #pragma unroll
            for (int mi = 0; mi < 2; ++mi)
                #pragma unroll
                for (int ni = 0; ni < 4; ++ni)
                    acc1[mi][ni] = __builtin_amdgcn_mfma_f32_16x16x32_bf16(af[mi], bf[ni], acc1[mi][ni], 0, 0, 0);
        }
    }
}

// ---- fused QKV projection, dual-output blocks, XCD-pinned (r7-verified) --
// 768 blocks x 512 thr = exactly 3 blocks/CU of uniform work.
//  bid<512 (z01): x m-panel staged once vs wq AND wk -> Q and K tiles.
//  bid>=512 (z2f): wv m-tile staged once vs TWO x n-tiles -> 2 Vt tiles.
__global__ __launch_bounds__(512, 4) void gemm_qkv(const u16* __restrict__ xb,
                                                   const u16* __restrict__ wq,
                                                   const u16* __restrict__ wk,
                                                   const u16* __restrict__ wv,
                                                   u16* __restrict__ Qb, u16* __restrict__ Kb,
                                                   u16* __restrict__ Vtb) {
    __shared__ __align__(16) u16 As [8192];
    __shared__ __align__(16) u16 Bs0[8192];
    __shared__ __align__(16) u16 Bs1[8192];
    const int bid = blockIdx.x;

    f32x4 acc0[2][4], acc1[2][4];
    #pragma unroll
    for (int a = 0; a < 2; ++a)
        #pragma unroll
        for (int b = 0; b < 4; ++b) { acc0[a][b] = 0; acc1[a][b] = 0; }

    const int lane = threadIdx.x & 63, lr = lane & 15, quad = lane >> 4;
    const int wid = threadIdx.x >> 6;
    const int wm = (wid >> 1) * 32, wn = (wid & 1) * 64;

    if (bid < 512) {                          // ---- z0+z1: Q and K ----
        const int xcd = bid & 7;
        const int i   = bid >> 3;             // 0..63
        const int m0  = (xcd * 8 + (i & 7)) * 128;
        const int n0  = (i >> 3) * 128;
        core_dual(xb, wq, wk, m0, n0, n0, As, Bs0, Bs1, acc0, acc1);
        #pragma unroll
        for (int mi = 0; mi < 2; ++mi)
            #pragma unroll
            for (int ni = 0; ni < 4; ++ni)
                #pragma unroll
                for (int reg = 0; reg < 4; ++reg) {
                    int row = m0 + wm + mi * 16 + quad * 4 + reg;
                    int col = n0 + wn + ni * 16 + lr;
                    int bhh = (row >> 11) * 16 + (col >> 6);
                    size_t o = (size_t)bhh * 131072 + (size_t)(row & 2047) * 64 + (col & 63);
                    Qb[o] = f2bf(acc0[mi][ni][reg] * 0.18033688f);   // 0.125*log2(e)
                    Kb[o] = f2bf(acc1[mi][ni][reg]);
                }
    } else {                                  // ---- z2 pair: two Vt tiles ----
        const int t   = bid - 512;
        const int xcd = t & 7;
        const int j   = t >> 3;               // 0..31
        const int m0  = (j & 7) * 128;        // wv rows
        const int np  = xcd * 4 + (j >> 3);   // x n-pair panel (256 rows)
        const int n0a = np * 256, n0b = np * 256 + 128;
        core_dual(wv, xb, xb, m0, n0a, n0b, As, Bs0, Bs1, acc0, acc1);
        #pragma unroll
        for (int half = 0; half < 2; ++half) {
            const int nb = half ? n0b : n0a;
            #pragma unroll
            for (int mi = 0; mi < 2; ++mi)
                #pragma unroll
                for (int ni = 0; ni < 4; ++ni)
                    #pragma unroll
                    for (int reg = 0; reg < 4; ++reg) {
                        int row = m0 + wm + mi * 16 + quad * 4 + reg;   // d-dim (0..1023)
                        int col = nb + wn + ni * 16 + lr;               // s-dim (0..8191)
                        int bhh = (col >> 11) * 16 + (row >> 6);
                        float v = half ? acc1[mi][ni][reg] : acc0[mi][ni][reg];
                        Vtb[(size_t)bhh * 131072 + (size_t)(row & 63) * 2048 + (col & 2047)] = f2bf(v);
                    }
        }
    }
}

// ---- output projection: r5-verified config, 512 blocks x 256 thr --------
// 2 blocks/CU (24 KB LDS) -> TLP hides the 2-barrier drains.
__global__ __launch_bounds__(256) void gemm_out(const u16* __restrict__ Ob,
                                                const u16* __restrict__ wo,
                                                float* __restrict__ C) {
    __shared__ __align__(16) u16 As[8192];
    __shared__ __align__(16) u16 Bs[8192];
    const int bid = blockIdx.x;
    const int xcd = bid & 7;
    const int i   = bid >> 3;            // 0..63
    const int mp  = xcd * 8 + (i & 7);   // m fastest within XCD
    const int m0  = mp * 128, n0 = (i >> 3) * 128;

    f32x4 acc[4][4];
    #pragma unroll
    for (int a = 0; a < 4; ++a)
        #pragma unroll
        for (int j = 0; j < 4; ++j) acc[a][j] = 0;

    gemm_core(Ob, wo, m0, n0, As, Bs, acc);

    const int lane = threadIdx.x & 63, lr = lane & 15, quad = lane >> 4;
    const int wv4 = threadIdx.x >> 6;
    const int wm = (wv4 >> 1) * 64, wn = (wv4 & 1) * 64;
    #pragma unroll
    for (int mi = 0; mi < 4; ++mi)
        #pragma unroll
        for (int ni = 0; ni < 4; ++ni)
            #pragma unroll
            for (int reg = 0; reg < 4; ++reg) {
                int row = m0 + wm + mi * 16 + quad * 4 + reg;
                int col = n0 + wn + ni * 16 + lr;
                C[(size_t)row * 1024 + col] = acc[mi][ni][reg];
            }
}

// ---- block-cooperative flash attention, 8 waves (256 q-rows) per block --
// V IS staged through LDS: the stage is a block-level read combiner (8 waves
// consume each 8 KB tile from LDS after ONE global fetch). r12's direct-L2
// V reads caused 8x read amplification + L2 thrash + O-write-line eviction
// amplification (WRITE_SIZE 23->162 MB, attn 60->158 us). r9-verified body.
__global__ __launch_bounds__(512, 4) void attn_flash(const u16* __restrict__ Q,
                                                     const u16* __restrict__ K,
                                                     const u16* __restrict__ Vt,
                                                     u16* __restrict__ O) {
    __shared__ __align__(16) u16 Kbuf[2][4096];    // 64 keys x 64 d, swizzled
    __shared__ __align__(16) u16 Vbuf[2][4096];    // 64 d x 64 keys, swizzled
    __shared__ __align__(16) u16 Ps[8][2048];      // per-wave P (32 q x 64 k), swizzled

    const int tid = threadIdx.x, wave = tid >> 6, lane = tid & 63;
    const int lr = lane & 15, quad = lane >> 4;
    const int bh = blockIdx.x & 63;                // bh%8 pinned -> XCD-local K/V in L2
    const int p  = blockIdx.x >> 6;                // 0..7
    const int qt8 = (p < 4) ? (7 - p) : (p - 4);   // first half heavy, second light
    const int qbase = qt8 * 256 + wave * 32;
    const size_t base = (size_t)bh * 131072;

    const int srow = lane >> 3;                    // 0..7
    const int scg  = (lane & 7) ^ srow;            // swizzled col-group

    const short8 onesv = {0x3f80, 0x3f80, 0x3f80, 0x3f80, 0x3f80, 0x3f80, 0x3f80, 0x3f80};

    // Q fragments (B-operand): q = qbase + qmi*16 + lr, k-chunk = c*32+quad*8
    short8 qf[2][2];
    #pragma unroll
    for (int qmi = 0; qmi < 2; ++qmi)
        #pragma unroll
        for (int c = 0; c < 2; ++c)
            qf[qmi][c] = *(const short8*)&Q[base + (size_t)(qbase + qmi * 16 + lr) * 64 + c * 32 + quad * 8];

    f32x4 oacc[4][2];
    #pragma unroll
    for (int i = 0; i < 4; ++i) { oacc[i][0] = 0; oacc[i][1] = 0; }
    f32x4 lacc[2];
    lacc[0] = 0; lacc[1] = 0;                      // row-sum accumulators (MFMA ones)

    const int jmax = 4 * qt8 + 3;
    const int r0 = wave * 8;                       // this wave's 8-row staging group

    // stage tile 0 into buffer 0 (each wave: 1 K-load + 1 V-load of 1 KB)
    gl_lds16(&K[base + (size_t)(r0 + srow) * 64 + scg * 8], &Kbuf[0][r0 * 64]);
    gl_lds16(&Vt[base + (size_t)(r0 + srow) * 2048 + scg * 8], &Vbuf[0][r0 * 64]);

    for (int j = 0; j <= jmax; ++j) {
        const int buf = j & 1;
        __syncthreads();                           // staged tile j is ready
        if (j < jmax) {                            // prefetch j+1 (flies during compute)
            const int nb = buf ^ 1;
            gl_lds16(&K[base + (size_t)((j + 1) * 64 + r0 + srow) * 64 + scg * 8], &Kbuf[nb][r0 * 64]);
            gl_lds16(&Vt[base + (size_t)(r0 + srow) * 2048 + (j + 1) * 64 + scg * 8], &Vbuf[nb][r0 * 64]);
        }

        if (j * 64 <= qbase + 31) {                // tile not fully masked for this wave
            f32x4 st[4][2];
            #pragma unroll
            for (int ni = 0; ni < 4; ++ni) { st[ni][0] = 0; st[ni][1] = 0; }
            __builtin_amdgcn_s_setprio(1);
            #pragma unroll
            for (int c = 0; c < 2; ++c) {
                short8 kf[4];
                #pragma unroll
                for (int ni = 0; ni < 4; ++ni)
                    kf[ni] = *(const short8*)&Kbuf[buf][(ni * 16 + lr) * 64 + (((c * 4 + quad) ^ (lr & 7)) * 8)];
                #pragma unroll
                for (int ni = 0; ni < 4; ++ni)
                    #pragma unroll
                    for (int qmi = 0; qmi < 2; ++qmi)
                        st[ni][qmi] = __builtin_amdgcn_mfma_f32_16x16x32_bf16(kf[ni], qf[qmi][c], st[ni][qmi], 0, 0, 0);
            }
            __builtin_amdgcn_s_setprio(0);

            if (j >= 4 * qt8) {                    // only the diagonal region masks
                #pragma unroll
                for (int ni = 0; ni < 4; ++ni)
                    #pragma unroll
                    for (int qmi = 0; qmi < 2; ++qmi)
                        #pragma unroll
                        for (int reg = 0; reg < 4; ++reg) {
                            int key = j * 64 + ni * 16 + quad * 4 + reg;
                            int q   = qbase + qmi * 16 + lr;
                            if (key > q) st[ni][qmi][reg] = -3.0e38f;   // exp2 -> 0
                        }
            }

            // P = exp2(st) directly; store truncated bf16 to Ps (same-wave region)
            #pragma unroll
            for (int qmi = 0; qmi < 2; ++qmi) {
                #pragma unroll
                for (int ni = 0; ni < 4; ++ni) {
                    unsigned u0 = __float_as_uint(EXP2F(st[ni][qmi][0]));
                    unsigned u1 = __float_as_uint(EXP2F(st[ni][qmi][1]));
                    unsigned u2 = __float_as_uint(EXP2F(st[ni][qmi][2]));
                    unsigned u3 = __float_as_uint(EXP2F(st[ni][qmi][3]));
                    uint2 pk;
                    pk.x = __builtin_amdgcn_perm(u1, u0, 0x07060302);
                    pk.y = __builtin_amdgcn_perm(u3, u2, 0x07060302);
                    int g8 = ni * 2 + (quad >> 1);
                    *(uint2*)&Ps[wave][qmi * 1024 + lr * 64 + ((g8 ^ (lr & 7)) * 8 + (quad & 1) * 4)] = pk;
                }
            }

            __builtin_amdgcn_s_setprio(1);
            #pragma unroll
            for (int c = 0; c < 2; ++c) {
                short8 pf[2];
                #pragma unroll
                for (int qmi = 0; qmi < 2; ++qmi)
                    pf[qmi] = *(const short8*)&Ps[wave][qmi * 1024 + lr * 64 + (((c * 4 + quad) ^ (lr & 7)) * 8)];
                #pragma unroll
                for (int dmi = 0; dmi < 4; ++dmi) {
                    short8 vf = *(const short8*)&Vbuf[buf][(dmi * 16 + lr) * 64 + (((c * 4 + quad) ^ (lr & 7)) * 8)];
                    #pragma unroll
                    for (int qmi = 0; qmi < 2; ++qmi)
                        oacc[dmi][qmi] = __builtin_amdgcn_mfma_f32_16x16x32_bf16(vf, pf[qmi], oacc[dmi][qmi], 0, 0, 0);
                }
                #pragma unroll
                for (int qmi = 0; qmi < 2; ++qmi)
                    lacc[qmi] = __builtin_amdgcn_mfma_f32_16x16x32_bf16(onesv, pf[qmi], lacc[qmi], 0, 0, 0);
            }
            __builtin_amdgcn_s_setprio(0);
        }
    }

    const int b = bh >> 4, h = bh & 15;
    #pragma unroll
    for (int qmi = 0; qmi < 2; ++qmi) {
        float rl = 1.0f / lacc[qmi][0];            // l[q=lr]; all regs identical
        int s = qbase + qmi * 16 + lr;
        #pragma unroll
        for (int dmi = 0; dmi < 4; ++dmi) {
            unsigned o0 = f2bf(oacc[dmi][qmi][0] * rl);
            unsigned o1 = f2bf(oacc[dmi][qmi][1] * rl);
            unsigned o2 = f2bf(oacc[dmi][qmi][2] * rl);
            unsigned o3 = f2bf(oacc[dmi][qmi][3] * rl);
            uint2 pk;
            pk.x = o0 | (o1 << 16);
            pk.y = o2 | (o3 << 16);
            *(uint2*)&O[((size_t)(b * 2048 + s)) * 1024 + h * 64 + dmi * 16 + quad * 4] = pk;
        }
    }
}

extern "C" void kernel_launch(void* const* d_in, const int* in_sizes, int n_in,
                              void* d_out, int out_size, void* d_ws, size_t ws_size,
                              hipStream_t stream) {
    const float* x  = (const float*)d_in[0];
    const float* Wq = (const float*)d_in[1];
    const float* Wk = (const float*)d_in[2];
    const float* Wv = (const float*)d_in[3];
    const float* Wo = (const float*)d_in[4];

    u16* xb  = (u16*)d_ws;
    u16* wqb = xb + 8388608;
    u16* wkb = wqb + 1048576;
    u16* wvb = wkb + 1048576;
    u16* wob = wvb + 1048576;
    u16* Qb  = wob + 1048576;
    u16* Kb  = Qb + 8388608;
    u16* Vtb = Kb + 8388608;
    u16* Ob  = xb;   // alias: x dead after gemm_qkv

    convert_all<<<6144, 256, 0, stream>>>(x, Wq, Wk, Wv, Wo, xb, wqb, wkb, wvb, wob);

    gemm_qkv<<<768, 512, 0, stream>>>(xb, wqb, wkb, wvb, Qb, Kb, Vtb);

    attn_flash<<<512, 512, 0, stream>>>(Qb, Kb, Vtb, Ob);

    gemm_out<<<512, 256, 0, stream>>>(Ob, wob, (float*)d_out);
}